// Round 6
// baseline (267.076 us; speedup 1.0000x reference)
//
#include <hip/hip_runtime.h>

// GQA_22436909154699: softmax over a size-1 axis == 1.0, so the reference
// reduces to  out[bl, g*512+h*64+d] = (x @ Wkv + bkv)[bl, g*128+64+d].
// => one (16384 x 2048) @ (2048 x 256) GEMM (v-cols only) + broadcast x8.
// R13 = R12 with ONE change: per-slab order is now
//   vmcnt(12) -> barrier -> ds_read(slab t)->regs -> STAGE(t+3) -> cvt+MFMA
// (R12 had STAGE before the ds_reads, giving the compiler a
// gload_lds -> ds_read aliasing pair in straight-line code; it inserts its
// own s_waitcnt vmcnt(0) before the ds_reads, draining ALL 18 in-flight
// DMAs every slab -> slab period ~= full load latency ~= 2450 cyc, which
// matches R12's 67us main loop and the 2.1-2.3 TB/s pin common to
// R7/R10/R12. m201's verified template orders ds-reads BEFORE the stage
// for exactly this reason.) Everything else identical to R12 (passing).

#define EMBED 2048
#define SV 272  // epilogue LDS row stride in floats

typedef _Float16 half8 __attribute__((ext_vector_type(8)));
typedef _Float16 half4v __attribute__((ext_vector_type(4)));
typedef float f32x4 __attribute__((ext_vector_type(4)));

#define GLOAD16(g, l)                                                      \
  __builtin_amdgcn_global_load_lds(                                        \
      (const __attribute__((address_space(1))) void*)(g),                  \
      (__attribute__((address_space(3))) void*)(l), 16, 0, 0)

// ---- pre-pass: Bt[n][k] (f16) = Wkv[k][vcol(n)], vcol(n)=(n>>6)*128+64+(n&63)
__global__ __launch_bounds__(256) void prep_b(const float* __restrict__ Wkv,
                                              _Float16* __restrict__ Bt) {
  const int t = threadIdx.x;
  const int kb = blockIdx.x * 4;  // 512 blocks cover k = 0..2047
  const int vcol = ((t >> 6) * 128) + 64 + (t & 63);
  float v[4];
#pragma unroll
  for (int i = 0; i < 4; ++i) v[i] = Wkv[(size_t)(kb + i) * 512 + vcol];
  half4v h;
#pragma unroll
  for (int i = 0; i < 4; ++i) h[i] = (_Float16)v[i];
  *(half4v*)&Bt[(size_t)t * EMBED + kb] = h;
}

// ---- main: 256 blocks, block = 64 rows x 256 cols, 4 waves (64 n-cols each)
__global__ __launch_bounds__(256) void gqa_main(
    const float* __restrict__ x, const _Float16* __restrict__ Bt,
    const float* __restrict__ bkv, float* __restrict__ out) {
  // ring: 4 x (A slab 64rows x 128B f32 = 8KB) + 4 x (B slab 256rows x 64B f16
  // = 16KB) = 96 KB -> hard 1 block/CU.
  __shared__ __align__(16) char smem[4 * 8192 + 4 * 16384];
  char* const Ab = smem;
  char* const Bb = smem + 4 * 8192;
  float* const Vs = (float*)smem;  // epilogue overlay [8][SV] = 8.7 KB

  const int tid = threadIdx.x;
  const int w = tid >> 6;    // wave: n-cols [w*64, w*64+64)
  const int lane = tid & 63;
  const int lm = lane & 15;
  const int lq = lane >> 4;
  const int row0 = blockIdx.x * 64;

  // ---- staging sources (per-lane, pre-swizzled cols); dest = base + lane*16
  // A instr i: row = w*16 + i*8 + (lane>>3); dest col (lane&7)*16;
  //            src col = dest ^ ((row&7)<<4), row&7 = lane>>3.
  const int acol = ((lane & 7) ^ (lane >> 3)) << 4;
  const char* asrc0 = (const char*)x +
      (size_t)(row0 + w * 16 + (lane >> 3)) * (EMBED * 4) + acol;
  const char* asrc1 = asrc0 + (size_t)8 * EMBED * 4;
  const int adst0 = (w * 16) * 128;        // + i*1024
  // B instr j: n = w*64 + j*16 + (lane>>2); dest col (lane&3)*16;
  //            src col = dest ^ (((n>>1)&3)<<4), (n>>1)&3 = (lane>>3)&3.
  const int bcol = (((lane & 3) << 4) ^ (((lane >> 3) & 3) << 4));
  const char* bsrc0 = (const char*)Bt +
      (size_t)(w * 64 + (lane >> 2)) * (EMBED * 2) + bcol;
  const int bdst0 = (w * 64) * 64;         // + j*1024

#define STAGE(b, s)                                                        \
  {                                                                        \
    const size_t sa_ = (size_t)(s) * 128; /* A k-bytes per slab */         \
    GLOAD16(asrc0 + sa_, Ab + (b) * 8192 + adst0);                         \
    GLOAD16(asrc1 + sa_, Ab + (b) * 8192 + adst0 + 1024);                  \
    const size_t sb_ = (size_t)(s) * 64;  /* B k-bytes per slab */         \
    GLOAD16(bsrc0 + sb_, Bb + (b) * 16384 + bdst0);                        \
    GLOAD16(bsrc0 + sb_ + (size_t)16 * EMBED * 2,                          \
            Bb + (b) * 16384 + bdst0 + 1024);                              \
    GLOAD16(bsrc0 + sb_ + (size_t)32 * EMBED * 2,                          \
            Bb + (b) * 16384 + bdst0 + 2048);                              \
    GLOAD16(bsrc0 + sb_ + (size_t)48 * EMBED * 2,                          \
            Bb + (b) * 16384 + bdst0 + 3072);                              \
  }

  // read swizzles (lane-const)
  const int arswz = (lm & 7) << 4;
  const int brswz = ((lm >> 1) & 3) << 4;

  f32x4 acc[4][4] = {};

  // prologue: stage slabs 0..2 (18 loads in flight)
  STAGE(0, 0);
  STAGE(1, 1);
  STAGE(2, 2);

  // steady state per slab t:
  //   vmcnt(12)  : slab t's 6 DMAs retired (18 -> 12 outstanding)
  //   barrier    : all waves' slab-t data visible in LDS
  //   ds_read(t) : hoist fragments to regs BEFORE any new gload is issued
  //   STAGE(t+3) : refill buffer (t+3)&3 (= (t-1)&3, consumed last iter)
  //   cvt + MFMA : pure reg work; compiler inserts lgkm waits only
  // Tail: junk re-stages of slab 63 keep vmcnt counts uniform.
  for (int tt = 0; tt < 64; tt += 4) {
#define ITER(T, BC, BS)                                                    \
    {                                                                      \
      asm volatile("s_waitcnt vmcnt(12)" ::: "memory");                    \
      __builtin_amdgcn_s_barrier();                                        \
      f32x4 a0r_[4], a1r_[4];                                              \
      half8 bfr_[4];                                                       \
      {                                                                    \
        const char* Ar_ = Ab + (BC) * 8192 + lm * 128;                     \
        const char* Br_ = Bb + (BC) * 16384 + (w * 64 + lm) * 64 +         \
                          ((lq << 4) ^ brswz);                             \
        _Pragma("unroll") for (int ni = 0; ni < 4; ++ni)                   \
            bfr_[ni] = *(const half8*)(Br_ + ni * 1024);                   \
        _Pragma("unroll") for (int mi = 0; mi < 4; ++mi) {                 \
          a0r_[mi] = *(const f32x4*)(Ar_ + mi * 2048 + ((lq << 5) ^ arswz)); \
          a1r_[mi] =                                                       \
              *(const f32x4*)(Ar_ + mi * 2048 + (((lq << 5) + 16) ^ arswz)); \
        }                                                                  \
      }                                                                    \
      {                                                                    \
        const int ss_ = (T) + 3 < 64 ? (T) + 3 : 63;                       \
        STAGE(BS, ss_);                                                    \
      }                                                                    \
      _Pragma("unroll") for (int mi = 0; mi < 4; ++mi) {                   \
        half8 af_;                                                         \
        _Pragma("unroll") for (int j = 0; j < 4; ++j)                      \
            af_[j] = (_Float16)a0r_[mi][j];                                \
        _Pragma("unroll") for (int j = 0; j < 4; ++j)                      \
            af_[4 + j] = (_Float16)a1r_[mi][j];                            \
        _Pragma("unroll") for (int ni = 0; ni < 4; ++ni)                   \
            acc[mi][ni] = __builtin_amdgcn_mfma_f32_16x16x32_f16(          \
                af_, bfr_[ni], acc[mi][ni], 0, 0, 0);                      \
      }                                                                    \
    }
    ITER(tt + 0, 0, 3)
    ITER(tt + 1, 1, 0)
    ITER(tt + 2, 2, 1)
    ITER(tt + 3, 3, 2)
#undef ITER
  }

  // epilogue: drain junk DMAs before overlaying smem with Vs
  asm volatile("s_waitcnt vmcnt(0)" ::: "memory");
  __syncthreads();

  float bias[4];
#pragma unroll
  for (int ni = 0; ni < 4; ++ni) bias[ni] = bkv[w * 128 + 64 + ni * 16 + lm];

  // 8 chunks of 8 rows: acc -> Vs (v-cols 0..255) -> broadcast x8 coalesced
#pragma unroll
  for (int c = 0; c < 8; ++c) {
    const int mi = c >> 1;  // compile-time after unroll
    if ((lq >> 1) == (c & 1)) {
#pragma unroll
      for (int ni = 0; ni < 4; ++ni) {
        const int n = w * 64 + ni * 16 + lm;
        f32x4 v = acc[mi][ni];
#pragma unroll
        for (int r = 0; r < 4; ++r)
          Vs[((lq & 1) * 4 + r) * SV + n] = v[r] + bias[ni];
      }
    }
    __syncthreads();
    f32x4* out4 = (f32x4*)(out + (size_t)(row0 + c * 8) * EMBED);
#pragma unroll 4
    for (int i = 0; i < 16; ++i) {
      const int f = i * 256 + tid;  // 8 rows x 512 float4
      const int row = f >> 9;
      const int c4 = f & 511;
      const int grp = c4 >> 7;
      const int d4 = c4 & 15;
      out4[(size_t)row * 512 + c4] =
          *(const f32x4*)&Vs[row * SV + grp * 64 + d4 * 4];
    }
    __syncthreads();
  }
}

extern "C" void kernel_launch(void* const* d_in, const int* in_sizes, int n_in,
                              void* d_out, int out_size, void* d_ws, size_t ws_size,
                              hipStream_t stream) {
  const float* x = (const float*)d_in[0];
  // d_in[1] = Wq, d_in[2] = bq : dead code (softmax over size-1 axis == 1)
  const float* Wkv = (const float*)d_in[3];
  const float* bkv = (const float*)d_in[4];
  float* out = (float*)d_out;
  _Float16* Bt = (_Float16*)d_ws;  // 256*2048 f16 = 1 MB scratch

  prep_b<<<512, 256, 0, stream>>>(Wkv, Bt);
  gqa_main<<<256, 256, 0, stream>>>(x, Bt, bkv, out);
}

// Round 7
// 262.274 us; speedup vs baseline: 1.0183x; 1.0183x over previous
//
#include <hip/hip_runtime.h>

// GQA_22436909154699: softmax over a size-1 axis == 1.0, so the reference
// reduces to  out[bl, g*512+h*64+d] = (x @ Wkv + bkv)[bl, g*128+64+d].
// => one (16384 x 2048) @ (2048 x 256) GEMM (v-cols only) + broadcast x8.
// R14: halve the barrier-phase count. Evidence: R7/R10/R12/R13 all cost
// ~2200-3300 cyc per barrier-delimited slab (issue work only ~600 cyc) at
// 2.1-2.3 TB/s, independent of occupancy / staging mechanism / intra-slab
// order (R13 null) -> fixed per-phase overhead dominates. So: BK 32->64
// (slab = 48 KB stored as TWO 32-k regions, each byte-identical to R12's
// verified layouts+swizzles), depth-3 ring = 144 KB LDS, 32 slabs, ONE
// barrier per slab (was 64). 12 DMAs/slab/wave, counted vmcnt(12) (24
// outstanding -> 12), junk tail stages keep counts uniform. Grid (256
// blocks, 64 rows x 256 cols, 1 blk/CU) and epilogue unchanged from R13.

#define EMBED 2048
#define SV 272  // epilogue LDS row stride in floats

typedef _Float16 half8 __attribute__((ext_vector_type(8)));
typedef _Float16 half4v __attribute__((ext_vector_type(4)));
typedef float f32x4 __attribute__((ext_vector_type(4)));

#define GLOAD16(g, l)                                                      \
  __builtin_amdgcn_global_load_lds(                                        \
      (const __attribute__((address_space(1))) void*)(g),                  \
      (__attribute__((address_space(3))) void*)(l), 16, 0, 0)

// ---- pre-pass: Bt[n][k] (f16) = Wkv[k][vcol(n)], vcol(n)=(n>>6)*128+64+(n&63)
__global__ __launch_bounds__(256) void prep_b(const float* __restrict__ Wkv,
                                              _Float16* __restrict__ Bt) {
  const int t = threadIdx.x;
  const int kb = blockIdx.x * 4;  // 512 blocks cover k = 0..2047
  const int vcol = ((t >> 6) * 128) + 64 + (t & 63);
  float v[4];
#pragma unroll
  for (int i = 0; i < 4; ++i) v[i] = Wkv[(size_t)(kb + i) * 512 + vcol];
  half4v h;
#pragma unroll
  for (int i = 0; i < 4; ++i) h[i] = (_Float16)v[i];
  *(half4v*)&Bt[(size_t)t * EMBED + kb] = h;
}

// ---- main: 256 blocks, block = 64 rows x 256 cols, 4 waves (64 n-cols each)
__global__ __launch_bounds__(256) void gqa_main(
    const float* __restrict__ x, const _Float16* __restrict__ Bt,
    const float* __restrict__ bkv, float* __restrict__ out) {
  // ring: 3 x (A slab 16KB = 2 regions of 64rows x 128B f32) +
  //       3 x (B slab 32KB = 2 regions of 256rows x 64B f16) = 144 KB.
  __shared__ __align__(16) char smem[3 * 16384 + 3 * 32768];
  char* const Ab = smem;
  char* const Bb = smem + 3 * 16384;
  float* const Vs = (float*)smem;  // epilogue overlay [8][SV] = 8.7 KB

  const int tid = threadIdx.x;
  const int w = tid >> 6;    // wave: n-cols [w*64, w*64+64)
  const int lane = tid & 63;
  const int lm = lane & 15;
  const int lq = lane >> 4;
  const int row0 = blockIdx.x * 64;

  // ---- staging sources (per-lane, pre-swizzled cols); dest = base + lane*16
  // A (per region): instr i covers rows w*16 + i*8 + (lane>>3), dest slot
  // (lane&7)*16B; src col = dest ^ ((row&7)<<4), row&7 = lane>>3.
  const int acol = ((lane & 7) ^ (lane >> 3)) << 4;
  const char* asrc = (const char*)x +
      (size_t)(row0 + w * 16 + (lane >> 3)) * (EMBED * 4) + acol;
  const int adst0 = (w * 16) * 128;  // + r*8192 + i*1024
  // B (per region): instr j covers rows w*64 + j*16 + (lane>>2), dest slot
  // (lane&3)*16B; src col = dest ^ (((row>>1)&3)<<4), (row>>1)&3=(lane>>3)&3.
  const int bcol = (((lane & 3) ^ ((lane >> 3) & 3)) << 4);
  const char* bsrc = (const char*)Bt +
      (size_t)(w * 64 + (lane >> 2)) * (EMBED * 2) + bcol;
  const int bdst0 = (w * 64) * 64;  // + r*16384 + j*1024

  // 12 DMAs per slab per wave: 4 A (2 regions x 2 instr) + 8 B (2 x 4).
#define STAGE(b, s)                                                        \
  {                                                                        \
    const char* as_ = asrc + (size_t)(s) * 256;                            \
    char* ad_ = Ab + (b) * 16384 + adst0;                                  \
    GLOAD16(as_, ad_);                                                     \
    GLOAD16(as_ + (size_t)8 * EMBED * 4, ad_ + 1024);                      \
    GLOAD16(as_ + 128, ad_ + 8192);                                        \
    GLOAD16(as_ + (size_t)8 * EMBED * 4 + 128, ad_ + 8192 + 1024);         \
    const char* bs_ = bsrc + (size_t)(s) * 128;                            \
    char* bd_ = Bb + (b) * 32768 + bdst0;                                  \
    GLOAD16(bs_, bd_);                                                     \
    GLOAD16(bs_ + (size_t)16 * EMBED * 2, bd_ + 1024);                     \
    GLOAD16(bs_ + (size_t)32 * EMBED * 2, bd_ + 2048);                     \
    GLOAD16(bs_ + (size_t)48 * EMBED * 2, bd_ + 3072);                     \
    GLOAD16(bs_ + 64, bd_ + 16384);                                        \
    GLOAD16(bs_ + (size_t)16 * EMBED * 2 + 64, bd_ + 16384 + 1024);        \
    GLOAD16(bs_ + (size_t)32 * EMBED * 2 + 64, bd_ + 16384 + 2048);        \
    GLOAD16(bs_ + (size_t)48 * EMBED * 2 + 64, bd_ + 16384 + 3072);        \
  }

  // read swizzles (lane-const), identical to R12/R13 per region
  const int arswz = (lm & 7) << 4;
  const int brswz = ((lm >> 1) & 3) << 4;

#define LOADFRAG(b, roa, rob)                                              \
  {                                                                        \
    const char* Ar_ = Ab + (b) * 16384 + (roa) + lm * 128;                 \
    const char* Br_ = Bb + (b) * 32768 + (rob) + (w * 64 + lm) * 64 +      \
                      ((lq << 4) ^ brswz);                                 \
    _Pragma("unroll") for (int ni = 0; ni < 4; ++ni)                       \
        bfr_[ni] = *(const half8*)(Br_ + ni * 1024);                       \
    _Pragma("unroll") for (int mi = 0; mi < 4; ++mi) {                     \
      a0r_[mi] = *(const f32x4*)(Ar_ + mi * 2048 + ((lq << 5) ^ arswz));   \
      a1r_[mi] =                                                           \
          *(const f32x4*)(Ar_ + mi * 2048 + (((lq << 5) + 16) ^ arswz));   \
    }                                                                      \
  }
#define MFMAFRAG()                                                         \
  _Pragma("unroll") for (int mi = 0; mi < 4; ++mi) {                       \
    half8 af_;                                                             \
    _Pragma("unroll") for (int j = 0; j < 4; ++j)                          \
        af_[j] = (_Float16)a0r_[mi][j];                                    \
    _Pragma("unroll") for (int j = 0; j < 4; ++j)                          \
        af_[4 + j] = (_Float16)a1r_[mi][j];                                \
    _Pragma("unroll") for (int ni = 0; ni < 4; ++ni)                       \
        acc[mi][ni] = __builtin_amdgcn_mfma_f32_16x16x32_f16(              \
            af_, bfr_[ni], acc[mi][ni], 0, 0, 0);                          \
  }

  f32x4 acc[4][4] = {};

  // prologue: stage slabs 0,1 (24 DMAs in flight per wave)
  STAGE(0, 0);
  STAGE(1, 1);

  // per slab t: vmcnt(12) [slab t's 12 retired] -> barrier -> region-0
  // reads -> STAGE(t+2 into buf (t+2)%3 = slab t-1's, consumed last iter)
  // -> region-0 MFMA -> region-1 reads -> region-1 MFMA. ONE barrier/slab.
#define ITER(T, BC, BS)                                                    \
  {                                                                        \
    asm volatile("s_waitcnt vmcnt(12)" ::: "memory");                      \
    __builtin_amdgcn_s_barrier();                                          \
    f32x4 a0r_[4], a1r_[4];                                                \
    half8 bfr_[4];                                                         \
    LOADFRAG(BC, 0, 0);                                                    \
    {                                                                      \
      const int ss_ = (T) + 2 < 32 ? (T) + 2 : 31;                         \
      STAGE(BS, ss_);                                                      \
    }                                                                      \
    MFMAFRAG();                                                            \
    LOADFRAG(BC, 8192, 16384);                                             \
    MFMAFRAG();                                                            \
  }

  for (int tt = 0; tt < 30; tt += 3) {
    ITER(tt + 0, 0, 2)
    ITER(tt + 1, 1, 0)
    ITER(tt + 2, 2, 1)
  }
  ITER(30, 0, 2)
  ITER(31, 1, 0)
#undef ITER

  // epilogue: drain junk DMAs before overlaying smem with Vs
  asm volatile("s_waitcnt vmcnt(0)" ::: "memory");
  __syncthreads();

  float bias[4];
#pragma unroll
  for (int ni = 0; ni < 4; ++ni) bias[ni] = bkv[w * 128 + 64 + ni * 16 + lm];

  // 8 chunks of 8 rows: acc -> Vs (v-cols 0..255) -> broadcast x8 coalesced
#pragma unroll
  for (int c = 0; c < 8; ++c) {
    const int mi = c >> 1;  // compile-time after unroll
    if ((lq >> 1) == (c & 1)) {
#pragma unroll
      for (int ni = 0; ni < 4; ++ni) {
        const int n = w * 64 + ni * 16 + lm;
        f32x4 v = acc[mi][ni];
#pragma unroll
        for (int r = 0; r < 4; ++r)
          Vs[((lq & 1) * 4 + r) * SV + n] = v[r] + bias[ni];
      }
    }
    __syncthreads();
    f32x4* out4 = (f32x4*)(out + (size_t)(row0 + c * 8) * EMBED);
#pragma unroll 4
    for (int i = 0; i < 16; ++i) {
      const int f = i * 256 + tid;  // 8 rows x 512 float4
      const int row = f >> 9;
      const int c4 = f & 511;
      const int grp = c4 >> 7;
      const int d4 = c4 & 15;
      out4[(size_t)row * 512 + c4] =
          *(const f32x4*)&Vs[row * SV + grp * 64 + d4 * 4];
    }
    __syncthreads();
  }
}

extern "C" void kernel_launch(void* const* d_in, const int* in_sizes, int n_in,
                              void* d_out, int out_size, void* d_ws, size_t ws_size,
                              hipStream_t stream) {
  const float* x = (const float*)d_in[0];
  // d_in[1] = Wq, d_in[2] = bq : dead code (softmax over size-1 axis == 1)
  const float* Wkv = (const float*)d_in[3];
  const float* bkv = (const float*)d_in[4];
  float* out = (float*)d_out;
  _Float16* Bt = (_Float16*)d_ws;  // 256*2048 f16 = 1 MB scratch

  prep_b<<<512, 256, 0, stream>>>(Wkv, Bt);
  gqa_main<<<256, 256, 0, stream>>>(x, Bt, bkv, out);
}